// Round 8
// baseline (464.361 us; speedup 1.0000x reference)
//
#include <hip/hip_runtime.h>
#include <hip/hip_bf16.h>
#include <hip/hip_fp16.h>
#include <string.h>

typedef __hip_bfloat16 bf16;
typedef _Float16 f16;
typedef __attribute__((ext_vector_type(8))) short short8;
typedef __attribute__((ext_vector_type(4))) float floatx4;
typedef __attribute__((ext_vector_type(4))) unsigned int uintx4;

// async global->LDS, 16B per lane; LDS dest is wave-uniform base + lane*16
#define GLD16(gp, lp) __builtin_amdgcn_global_load_lds( \
    (__attribute__((address_space(1))) void*)(gp),      \
    (__attribute__((address_space(3))) void*)(lp), 16, 0, 0)

__device__ __forceinline__ unsigned short bf16_bits(float f) {
  bf16 h = (bf16)f;
  unsigned short s;
  memcpy(&s, &h, 2);
  return s;
}
__device__ __forceinline__ __half2 u2h2(unsigned u) {
  __half2 h;
  memcpy(&h, &u, 4);
  return h;
}

// ---------------------------------------------------------------------------
// x (f32, [4][4096][1024]) -> bf16. Batch b lands at outbase + b*bstride.
// ---------------------------------------------------------------------------
__global__ __launch_bounds__(256)
void cvtx_k(const float* __restrict__ x, char* __restrict__ outbase,
            size_t bstride) {
  size_t e = ((size_t)blockIdx.x * 256 + threadIdx.x) * 8;
  int b = (int)(e >> 22);                       // 4M elements per batch
  size_t i = e & 4194303;
  const floatx4* s = (const floatx4*)(x + e);
  floatx4 a0 = s[0], a1 = s[1];
  union { uintx4 u4; unsigned short us[8]; } w;
  w.us[0] = bf16_bits(a0.x); w.us[1] = bf16_bits(a0.y);
  w.us[2] = bf16_bits(a0.z); w.us[3] = bf16_bits(a0.w);
  w.us[4] = bf16_bits(a1.x); w.us[5] = bf16_bits(a1.y);
  w.us[6] = bf16_bits(a1.z); w.us[7] = bf16_bits(a1.w);
  *(uintx4*)((bf16*)(outbase + (size_t)b * bstride) + i) = w.u4;
}

// ---------------------------------------------------------------------------
// Transpose+convert 1024x1024 f32 weights: T[n][k] = bf16(W[k][n]), 3 via z.
// ---------------------------------------------------------------------------
__global__ __launch_bounds__(256)
void transpose_k(const float* __restrict__ W0, const float* __restrict__ W1,
                 const float* __restrict__ W2, bf16* __restrict__ T0,
                 bf16* __restrict__ T1, bf16* __restrict__ T2) {
  __shared__ bf16 t[64][66];                 // +2 pad: conflict-free col reads
  const float* S = blockIdx.z == 0 ? W0 : (blockIdx.z == 1 ? W1 : W2);
  bf16* Dst      = blockIdx.z == 0 ? T0 : (blockIdx.z == 1 ? T1 : T2);
  const int tx = threadIdx.x & 63, ty = threadIdx.x >> 6;
  const int kb = blockIdx.y * 64, nb = blockIdx.x * 64;
#pragma unroll
  for (int rr = 0; rr < 16; ++rr) {
    int r = ty * 16 + rr;
    t[r][tx] = (bf16)S[(size_t)(kb + r) * 1024 + nb + tx];
  }
  __syncthreads();
#pragma unroll
  for (int rr = 0; rr < 16; ++rr) {
    int r = ty * 16 + rr;
    Dst[(size_t)(nb + r) * 1024 + kb + tx] = t[tx][r];
  }
}

// ---------------------------------------------------------------------------
// h_prep[dblk64][k][dd] = f16( h_filter[k][dblk*64+dd] * exp(-0.01k) ), k<512
// ---------------------------------------------------------------------------
__global__ __launch_bounds__(256)
void hprep_k(const float* __restrict__ hf, f16* __restrict__ hp) {
  int idx = blockIdx.x * 256 + threadIdx.x;   // < 16*512*64
  int dblk = idx >> 15;
  int rem = idx & 32767;
  int k = rem >> 6, dd = rem & 63;
  int d = dblk * 64 + dd;
  float val = hf[(size_t)k * 1024 + d] * __expf(-0.01f * (float)k);
  hp[idx] = (f16)val;
}

// ---------------------------------------------------------------------------
// 256x256 GEMM body (round-6 form, best measured; kept verbatim this round).
//   C[m0..+256][n0..+256] = A[M][1024](bf16) @ Bt[1024][1024]^T + bias
// 512 threads = 8 waves (2M x 4N), per-wave 128x64 output, acc[8][4] 16x16.
// BK=64, K=1024 -> 16 K-tiles; LDS double-buffered (A,B: 2x32KB each=128KB).
// Loop: STAGE(slot^1, kt+1) -> s_waitcnt vmcnt(8) -> s_barrier ->
//       ds_read+MFMA -> s_barrier.  vmcnt(8) waits only for the previous
// tile's 8 loads; the 8 newest stay in flight across the barriers.
//
// LDS layout: 16B granule (m,q) stored at slot m*8 + (q^(m&7)); gld_lds
// writes linear lane-order, per-lane GLOBAL src permuted to match.
// Fragment reads hit each 4-bank quad exactly 8x (2 lanes/bank = free).
// out_mode: 0 bf16, 1 f16, 2 f32 store.
// ---------------------------------------------------------------------------
__device__ __forceinline__
void gemm_body256(const bf16* __restrict__ A, const bf16* __restrict__ Bt,
                  const float* __restrict__ bias, void* __restrict__ Cout,
                  int out_mode, int m0, int n0) {
  constexpr int K = 1024;
  __shared__ __align__(16) bf16 Asl[2][16384];   // 2 x 32KB
  __shared__ __align__(16) bf16 Bsl[2][16384];   // 2 x 32KB
  const int tid = threadIdx.x;                   // 0..511
  const int lane = tid & 63;
  const int wave = tid >> 6;                     // 0..7
  const int wm = wave >> 2, wn = wave & 3;       // 2M x 4N
  const int r = lane & 15, qlane = lane >> 4;    // frag row / 16B k-chunk

  floatx4 acc[8][4] = {};

  // ---- staging source pointers: slot p = is*512 + tid ----
  const bf16* gA[4];
  const bf16* gB[4];
#pragma unroll
  for (int is = 0; is < 4; ++is) {
    int p = is * 512 + tid;
    int m = p >> 3;
    int qe = (p & 7) ^ (m & 7);
    gA[is] = A  + (size_t)(m0 + m) * K + qe * 8;
    gB[is] = Bt + (size_t)(n0 + m) * K + qe * 8;
  }
  const int wbyte = wave * 1024;   // wave-uniform LDS base component

  // ---- fragment read byte-offsets (granule-permuted layout) ----
  const int rx = r & 7;
  const int aRow = (wm * 128 + r) * 128;         // A row base (bytes)
  const int bRow = (wn * 64 + r) * 128;          // B row base (bytes)
  const int a0off = aRow + ((qlane) ^ rx) * 16;        // ks=0
  const int a1off = aRow + ((4 + qlane) ^ rx) * 16;    // ks=1
  const int b0off = bRow + ((qlane) ^ rx) * 16;
  const int b1off = bRow + ((4 + qlane) ^ rx) * 16;

  // ---- prologue: stage K-tile 0 into buffer 0 (8 gld_lds per wave) ----
#pragma unroll
  for (int is = 0; is < 4; ++is)
    GLD16(gA[is], (char*)&Asl[0][0] + is * 8192 + wbyte);
#pragma unroll
  for (int is = 0; is < 4; ++is)
    GLD16(gB[is], (char*)&Bsl[0][0] + is * 8192 + wbyte);

  for (int kt = 0; kt < 16; ++kt) {
    const int cur = kt & 1;
    const char* Ab = (const char*)&Asl[cur][0];
    const char* Bb = (const char*)&Bsl[cur][0];

    // stage tile kt+1 into slot cur^1 (released by previous tail barrier),
    // then wait ONLY for tile kt's 8 loads.
    if (kt < 15) {
      const int k0 = (kt + 1) * 64;
#pragma unroll
      for (int is = 0; is < 4; ++is)
        GLD16(gA[is] + k0, (char*)&Asl[cur ^ 1][0] + is * 8192 + wbyte);
#pragma unroll
      for (int is = 0; is < 4; ++is)
        GLD16(gB[is] + k0, (char*)&Bsl[cur ^ 1][0] + is * 8192 + wbyte);
      asm volatile("s_waitcnt vmcnt(8)" ::: "memory");
    } else {
      asm volatile("s_waitcnt vmcnt(0)" ::: "memory");
    }
    __builtin_amdgcn_s_barrier();          // tile kt visible to all waves

    // ---- phase ks=0 ----
    {
      short8 af[8], bfr[4];
#pragma unroll
      for (int i = 0; i < 8; ++i)
        af[i] = *(const short8*)(Ab + a0off + i * 2048);
#pragma unroll
      for (int j = 0; j < 4; ++j)
        bfr[j] = *(const short8*)(Bb + b0off + j * 2048);
      __builtin_amdgcn_s_setprio(1);
#pragma unroll
      for (int i = 0; i < 8; ++i)
#pragma unroll
        for (int j = 0; j < 4; ++j)
          acc[i][j] = __builtin_amdgcn_mfma_f32_16x16x32_bf16(
              af[i], bfr[j], acc[i][j], 0, 0, 0);
      __builtin_amdgcn_s_setprio(0);
    }
    // ---- phase ks=1 ----
    {
      short8 af[8], bfr[4];
#pragma unroll
      for (int i = 0; i < 8; ++i)
        af[i] = *(const short8*)(Ab + a1off + i * 2048);
#pragma unroll
      for (int j = 0; j < 4; ++j)
        bfr[j] = *(const short8*)(Bb + b1off + j * 2048);
      __builtin_amdgcn_s_setprio(1);
#pragma unroll
      for (int i = 0; i < 8; ++i)
#pragma unroll
        for (int j = 0; j < 4; ++j)
          acc[i][j] = __builtin_amdgcn_mfma_f32_16x16x32_bf16(
              af[i], bfr[j], acc[i][j], 0, 0, 0);
      __builtin_amdgcn_s_setprio(0);
    }
    __builtin_amdgcn_s_barrier();          // slot cur released for restaging
  }

  // ---- epilogue: C/D layout col(n)=lane&15, row(m)=(lane>>4)*4+reg ----
  const int cb = n0 + wn * 64;
  float bvv[4];
#pragma unroll
  for (int j = 0; j < 4; ++j) bvv[j] = bias[cb + j * 16 + r];
#pragma unroll
  for (int i = 0; i < 8; ++i) {
    int rowb = m0 + wm * 128 + i * 16 + qlane * 4;
#pragma unroll
    for (int j = 0; j < 4; ++j) {
      int col = cb + j * 16 + r;
#pragma unroll
      for (int v = 0; v < 4; ++v) {
        float val = acc[i][j][v] + bvv[j];
        size_t off = (size_t)(rowb + v) * 1024 + col;
        if (out_mode == 0)      ((bf16*)Cout)[off] = (bf16)val;
        else if (out_mode == 1) ((f16*)Cout)[off] = (f16)val;
        else                    ((float*)Cout)[off] = val;
      }
    }
  }
}

// u and v projections fused via grid.z (0: u bf16, 1: v f16).
__global__ __launch_bounds__(512, 2)
void gemm_uv_k(const bf16* __restrict__ A, const bf16* __restrict__ WuT,
               const bf16* __restrict__ WvT, const float* __restrict__ bu,
               const float* __restrict__ bv, bf16* __restrict__ u_out,
               f16* __restrict__ v_out) {
  const int isv = blockIdx.z;
  gemm_body256(A, isv ? WvT : WuT, isv ? bv : bu,
               isv ? (void*)v_out : (void*)u_out, isv,
               blockIdx.x * 256, blockIdx.y * 256);
}

// final projection: C f32
__global__ __launch_bounds__(512, 2)
void gemm_o_k(const bf16* __restrict__ A, const bf16* __restrict__ Bt,
              const float* __restrict__ bias, float* __restrict__ C) {
  gemm_body256(A, Bt, bias, (void*)C, 2, blockIdx.x * 256, blockIdx.y * 256);
}

// ---------------------------------------------------------------------------
// Truncated causal depthwise conv (T=512) + gate, packed f16x2 along d.
// Block: 64 d (32 __half2 pairs) x 128 t; thread: 1 d-pair, 16 t.
// Chunk = 64 lags; acc in f16x2 per chunk, flushed to f32. All inner-loop
// math is v_pk_fma_f16 (2 MACs/inst); zero cvts in the hot loop.
// LDS: vs 192x32 u32 (24KB) + hs 64x32 u32 (8KB) = 32KB -> 5 blocks/CU.
// (Invariant at ~182 us across 3 structural rewrites; kept verbatim.
//  Round-8: launched per-batch (4 dispatches of ~46 us) so the GEMM
//  dispatches surface in the rocprof top-5 -- work is identical.)
// ---------------------------------------------------------------------------
__global__ __launch_bounds__(256)
void conv_k(const f16* __restrict__ vg0, const f16* __restrict__ hp,
            bf16* __restrict__ up0) {
  constexpr int CC = 64, TT = 128, D = 1024;
  __shared__ __align__(16) unsigned vs2[(TT + CC) * 32];  // [row][pair] 24KB
  __shared__ __align__(16) unsigned hs2[CC * 32];         // [kk][pair]   8KB
  const int tid = threadIdx.x;
  const int pp = tid & 31, tg = tid >> 5;
  const int bx = blockIdx.x;                 // d0 = bx*64
  const int t0 = blockIdx.y * TT;
  const int base = tg * 16;
  const unsigned* vg32 = (const unsigned*)(vg0 + (size_t)blockIdx.z * 4096 * D);
  unsigned* up32 = (unsigned*)(up0 + (size_t)blockIdx.z * 4096 * D);
  const uintx4* vg4 = (const uintx4*)vg32;             // 128 u4 per t-row
  const uintx4* hp4 = (const uintx4*)hp + (size_t)bx * 512 * 8;  // 8 u4/row

  float ax[16], ay[16];
#pragma unroll
  for (int i = 0; i < 16; ++i) { ax[i] = 0.f; ay[i] = 0.f; }

  for (int c = 0; c < 8; ++c) {
    const int k0 = c * CC;
    __syncthreads();   // prev chunk's reads complete before restage
    {  // stage h chunk: 64 rows x 8 u4 = 512 u4
      uintx4* hd = (uintx4*)hs2;
      hd[tid] = hp4[k0 * 8 + tid];
      hd[tid + 256] = hp4[k0 * 8 + tid + 256];
    }
    {  // stage v window rows [t0-k0-64, t0+127]: 192 x 8 u4 = 1536 u4
      uintx4* vd = (uintx4*)vs2;
#pragma unroll
      for (int it = 0; it < 6; ++it) {
        int q = it * 256 + tid;
        int row = q >> 3, dp4 = q & 7;
        int tau = t0 - k0 - CC + row;
        uintx4 val = {0, 0, 0, 0};
        if (tau >= 0) val = vg4[(size_t)tau * 128 + bx * 8 + dp4];
        vd[q] = val;
      }
    }
    __syncthreads();

    __half2 p[16];
#pragma unroll
    for (int i = 0; i < 16; ++i)
      p[i] = u2h2(vs2[(base + i + CC) * 32 + pp]);     // v[t_i - k0]
    __half2 acc2[16];
    const __half2 z2 = __float2half2_rn(0.f);
#pragma unroll
    for (int i = 0; i < 16; ++i) acc2[i] = z2;

    for (int kb = 0; kb < 4; ++kb) {
#pragma unroll
      for (int k2 = 0; k2 < 16; ++k2) {
        const int kk = kb * 16 + k2;
        __half2 hk = u2h2(hs2[kk * 32 + pp]);
#pragma unroll
        for (int i = 0; i < 16; ++i)
          acc2[i] = __hfma2(hk, p[(i - k2) & 15], acc2[i]);
        p[(15 - k2) & 15] = u2h2(vs2[(base + CC - 1 - kk) * 32 + pp]);
      }
    }
#pragma unroll
    for (int i = 0; i < 16; ++i) {
      ax[i] += __low2float(acc2[i]);
      ay[i] += __high2float(acc2[i]);
    }
  }

  // gate: p = u * v_conv, in-place over u; one u32 = 2 bf16 per row
  const size_t rb = (size_t)(t0 + base) * 512 + bx * 32 + pp;
#pragma unroll
  for (int i = 0; i < 16; ++i) {
    unsigned uw = up32[rb + (size_t)i * 512];
    float ul = __uint_as_float((uw & 0xffffu) << 16);
    float uh = __uint_as_float(uw & 0xffff0000u);
    unsigned lo = bf16_bits(ul * ax[i]);
    unsigned hi = bf16_bits(uh * ay[i]);
    up32[rb + (size_t)i * 512] = lo | (hi << 16);
  }
}

// ---------------------------------------------------------------------------
// All inputs/outputs are FLOAT32. Internals bf16/f16.
// BIG path (ws_size >= 41 MB): full-M merged dispatches.
//   ws:   WuT 0..2MB | WvT 2..4 | WoT 4..6 | hp 6..7 | u 8..40MB (bf16)
//   d_out: xb (bf16) 0..32MB | v (f16) 32..64MB; gemm_o overwrites with f32.
// COMPACT path: per-batch loop.
// ---------------------------------------------------------------------------
extern "C" void kernel_launch(void* const* d_in, const int* in_sizes, int n_in,
                              void* d_out, int out_size, void* d_ws,
                              size_t ws_size, hipStream_t stream) {
  const float* x  = (const float*)d_in[0];
  const float* Wu = (const float*)d_in[1];
  const float* bu = (const float*)d_in[2];
  const float* Wv = (const float*)d_in[3];
  const float* bv = (const float*)d_in[4];
  const float* hf = (const float*)d_in[5];
  const float* Wo = (const float*)d_in[6];
  const float* bo = (const float*)d_in[7];
  char* ws = (char*)d_ws;
  bf16* WuT = (bf16*)(ws);
  bf16* WvT = (bf16*)(ws + 2097152);
  bf16* WoT = (bf16*)(ws + 4194304);
  f16*  hp  = (f16*)(ws + 6291456);

  dim3 tb(256);
  dim3 tg(512);
  transpose_k<<<dim3(16, 16, 3), tb, 0, stream>>>(Wu, Wv, Wo, WuT, WvT, WoT);
  hprep_k<<<dim3(2048), tb, 0, stream>>>(hf, hp);

  if (ws_size >= 42991616ull) {           // BIG: 41 MB needed
    bf16* xb = (bf16*)d_out;
    f16*  vf = (f16*)((char*)d_out + 33554432);
    bf16* u  = (bf16*)(ws + 8388608);
    cvtx_k<<<dim3(8192), tb, 0, stream>>>(x, (char*)d_out, 8388608);
    gemm_uv_k<<<dim3(64, 4, 2), tg, 0, stream>>>(xb, WuT, WvT, bu, bv, u, vf);
    // conv per batch (4 dispatches): identical work, surfaces GEMM counters
    for (int b = 0; b < 4; ++b)
      conv_k<<<dim3(16, 32, 1), tb, 0, stream>>>(vf + (size_t)b * 4194304,
                                                 hp, u + (size_t)b * 4194304);
    gemm_o_k<<<dim3(64, 4), tg, 0, stream>>>(u, WoT, bo, (float*)d_out);
  } else {                                // COMPACT: per-batch loop
    bf16* u_b = (bf16*)(ws + 8388608);
    cvtx_k<<<dim3(8192), tb, 0, stream>>>(x, (char*)d_out, 16777216);
    for (int b = 0; b < 4; ++b) {
      char* quarter = (char*)d_out + (size_t)b * 16777216;
      bf16* xb = (bf16*)quarter;
      f16*  vb = (f16*)(quarter + 8388608);
      float* outb = (float*)d_out + (size_t)b * 4194304;
      gemm_uv_k<<<dim3(16, 4, 2), tg, 0, stream>>>(xb, WuT, WvT, bu, bv,
                                                   u_b, vb);
      conv_k<<<dim3(16, 32, 1), tb, 0, stream>>>(vb, hp, u_b);
      gemm_o_k<<<dim3(16, 4), tg, 0, stream>>>(u_b, WoT, bo, outb);
    }
  }
}

// Round 9
// 417.871 us; speedup vs baseline: 1.1113x; 1.1113x over previous
//
#include <hip/hip_runtime.h>
#include <hip/hip_bf16.h>
#include <hip/hip_fp16.h>
#include <string.h>

typedef __hip_bfloat16 bf16;
typedef _Float16 f16;
typedef __attribute__((ext_vector_type(8))) short short8;
typedef __attribute__((ext_vector_type(4))) float floatx4;
typedef __attribute__((ext_vector_type(4))) unsigned int uintx4;

// async global->LDS, 16B per lane; LDS dest is wave-uniform base + lane*16
#define GLD16(gp, lp) __builtin_amdgcn_global_load_lds( \
    (__attribute__((address_space(1))) void*)(gp),      \
    (__attribute__((address_space(3))) void*)(lp), 16, 0, 0)

__device__ __forceinline__ unsigned short bf16_bits(float f) {
  bf16 h = (bf16)f;
  unsigned short s;
  memcpy(&s, &h, 2);
  return s;
}
__device__ __forceinline__ __half2 u2h2(unsigned u) {
  __half2 h;
  memcpy(&h, &u, 4);
  return h;
}

// ---------------------------------------------------------------------------
// x (f32, [4][4096][1024]) -> bf16. Batch b lands at outbase + b*bstride.
// ---------------------------------------------------------------------------
__global__ __launch_bounds__(256)
void cvtx_k(const float* __restrict__ x, char* __restrict__ outbase,
            size_t bstride) {
  size_t e = ((size_t)blockIdx.x * 256 + threadIdx.x) * 8;
  int b = (int)(e >> 22);                       // 4M elements per batch
  size_t i = e & 4194303;
  const floatx4* s = (const floatx4*)(x + e);
  floatx4 a0 = s[0], a1 = s[1];
  union { uintx4 u4; unsigned short us[8]; } w;
  w.us[0] = bf16_bits(a0.x); w.us[1] = bf16_bits(a0.y);
  w.us[2] = bf16_bits(a0.z); w.us[3] = bf16_bits(a0.w);
  w.us[4] = bf16_bits(a1.x); w.us[5] = bf16_bits(a1.y);
  w.us[6] = bf16_bits(a1.z); w.us[7] = bf16_bits(a1.w);
  *(uintx4*)((bf16*)(outbase + (size_t)b * bstride) + i) = w.u4;
}

// ---------------------------------------------------------------------------
// Transpose+convert 1024x1024 f32 weights: T[n][k] = bf16(W[k][n]), 3 via z.
// ---------------------------------------------------------------------------
__global__ __launch_bounds__(256)
void transpose_k(const float* __restrict__ W0, const float* __restrict__ W1,
                 const float* __restrict__ W2, bf16* __restrict__ T0,
                 bf16* __restrict__ T1, bf16* __restrict__ T2) {
  __shared__ bf16 t[64][66];                 // +2 pad: conflict-free col reads
  const float* S = blockIdx.z == 0 ? W0 : (blockIdx.z == 1 ? W1 : W2);
  bf16* Dst      = blockIdx.z == 0 ? T0 : (blockIdx.z == 1 ? T1 : T2);
  const int tx = threadIdx.x & 63, ty = threadIdx.x >> 6;
  const int kb = blockIdx.y * 64, nb = blockIdx.x * 64;
#pragma unroll
  for (int rr = 0; rr < 16; ++rr) {
    int r = ty * 16 + rr;
    t[r][tx] = (bf16)S[(size_t)(kb + r) * 1024 + nb + tx];
  }
  __syncthreads();
#pragma unroll
  for (int rr = 0; rr < 16; ++rr) {
    int r = ty * 16 + rr;
    Dst[(size_t)(nb + r) * 1024 + kb + tx] = t[tx][r];
  }
}

// ---------------------------------------------------------------------------
// h_prep[dblk64][k][dd] = f16( h_filter[k][dblk*64+dd] * exp(-0.01k) ), k<512
// ---------------------------------------------------------------------------
__global__ __launch_bounds__(256)
void hprep_k(const float* __restrict__ hf, f16* __restrict__ hp) {
  int idx = blockIdx.x * 256 + threadIdx.x;   // < 16*512*64
  int dblk = idx >> 15;
  int rem = idx & 32767;
  int k = rem >> 6, dd = rem & 63;
  int d = dblk * 64 + dd;
  float val = hf[(size_t)k * 1024 + d] * __expf(-0.01f * (float)k);
  hp[idx] = (f16)val;
}

// ---------------------------------------------------------------------------
// GEMM body, round-9: occupancy-first geometry (the round-8 counters showed
// MfmaUtil 30 / VALU 17 / HBM 16 / Occupancy 21 -> latency-bound at 1
// block/CU with 2 waves/SIMD in lockstep; both LDS (128KB) and regs
// (acc[8][4]=128 AGPR + 112 VGPR = 240) capped occupancy).
//   C[m0..+256][n0..+128] = A[M][1024](bf16) @ Bt[1024][1024]^T + bias
// 512 threads = 8 waves (4M x 2N), per-wave 64x64 output, acc 4x4 16x16
// (64 AGPR; ~115 total regs -> 16 waves/CU allowed). BK=32, 32 K-tiles.
// LDS: A 256x32 (16KB) + B 128x32 (8KB), double-buffered = 48KB
// -> 2 blocks/CU (reg-capped). Co-resident unsynced blocks cover each
// other's barrier/LDS bubbles so LDS and MFMA pipes overlap (m114).
// Counted-vmcnt loop (3 gld_lds/wave/tile):
//   STAGE(slot^1, kt+1) -> s_waitcnt vmcnt(3) -> s_barrier ->
//   ds_read (8) + 16 MFMA -> s_barrier.
//
// LDS granule permutation (64B rows, 4x16B granules/row): granule (m,q)
// stored at position q^(m&3); gld_lds writes linear lane-order, per-lane
// GLOBAL src permuted to match. Fragment read addr = row*64 +
// ((qlane^(r&3))*16; bijective onto each contiguous 1KB region ->
// bank-equivalent to a linear b128 read (conflict-free; round-8: 0 cnf).
// out_mode: 0 bf16, 1 f16, 2 f32 store.
// ---------------------------------------------------------------------------
__device__ __forceinline__
void gemm_body_occ(const bf16* __restrict__ A, const bf16* __restrict__ Bt,
                   const float* __restrict__ bias, void* __restrict__ Cout,
                   int out_mode, int m0, int n0) {
  constexpr int K = 1024;
  __shared__ __align__(16) bf16 Asl[2][8192];    // 2 x 16KB (256 rows x 32)
  __shared__ __align__(16) bf16 Bsl[2][4096];    // 2 x  8KB (128 rows x 32)
  const int tid = threadIdx.x;                   // 0..511
  const int lane = tid & 63;
  const int wave = tid >> 6;                     // 0..7
  const int wm = wave >> 1, wn = wave & 1;       // 4M x 2N
  const int r = lane & 15, qlane = lane >> 4;    // frag row / 16B k-chunk

  floatx4 acc[4][4] = {};

  // ---- staging source pointers (granule-permuted global addresses) ----
  // A: slot p = is*512 + tid (is 0..1); B: slot p = tid.
  const bf16* gA[2];
#pragma unroll
  for (int is = 0; is < 2; ++is) {
    int p = is * 512 + tid;
    int m = p >> 2;
    int qe = (p & 3) ^ (m & 3);
    gA[is] = A + (size_t)(m0 + m) * K + qe * 8;
  }
  const bf16* gB0;
  {
    int m = tid >> 2;
    int qe = (tid & 3) ^ (m & 3);
    gB0 = Bt + (size_t)(n0 + m) * K + qe * 8;
  }
  const int wbyte = wave * 1024;   // wave-uniform LDS base component

  // ---- fragment read byte-offsets ----
  const int rx3 = r & 3;
  const int aRow = (wm * 64 + r) * 64;           // A row base (bytes)
  const int bRow = (wn * 64 + r) * 64;           // B row base (bytes)
  const int aoff = aRow + (qlane ^ rx3) * 16;
  const int boff = bRow + (qlane ^ rx3) * 16;

  // ---- prologue: stage K-tile 0 into buffer 0 (3 gld_lds per wave) ----
  GLD16(gA[0], (char*)&Asl[0][0] + wbyte);
  GLD16(gA[1], (char*)&Asl[0][0] + 8192 + wbyte);
  GLD16(gB0,  (char*)&Bsl[0][0] + wbyte);

  for (int kt = 0; kt < 32; ++kt) {
    const int cur = kt & 1;
    const char* Ab = (const char*)&Asl[cur][0];
    const char* Bb = (const char*)&Bsl[cur][0];

    if (kt < 31) {
      const int k0 = (kt + 1) * 32;
      GLD16(gA[0] + k0, (char*)&Asl[cur ^ 1][0] + wbyte);
      GLD16(gA[1] + k0, (char*)&Asl[cur ^ 1][0] + 8192 + wbyte);
      GLD16(gB0  + k0, (char*)&Bsl[cur ^ 1][0] + wbyte);
      asm volatile("s_waitcnt vmcnt(3)" ::: "memory");
    } else {
      asm volatile("s_waitcnt vmcnt(0)" ::: "memory");
    }
    __builtin_amdgcn_s_barrier();          // tile kt visible to all waves

    short8 af[4], bfr[4];
#pragma unroll
    for (int i = 0; i < 4; ++i)
      af[i] = *(const short8*)(Ab + aoff + i * 1024);
#pragma unroll
    for (int j = 0; j < 4; ++j)
      bfr[j] = *(const short8*)(Bb + boff + j * 1024);
    __builtin_amdgcn_s_setprio(1);
#pragma unroll
    for (int i = 0; i < 4; ++i)
#pragma unroll
      for (int j = 0; j < 4; ++j)
        acc[i][j] = __builtin_amdgcn_mfma_f32_16x16x32_bf16(
            af[i], bfr[j], acc[i][j], 0, 0, 0);
    __builtin_amdgcn_s_setprio(0);
    __builtin_amdgcn_s_barrier();          // slot cur released for restaging
  }

  // ---- epilogue: C/D layout col(n)=lane&15, row(m)=(lane>>4)*4+reg ----
  const int cb = n0 + wn * 64;
  float bvv[4];
#pragma unroll
  for (int j = 0; j < 4; ++j) bvv[j] = bias[cb + j * 16 + r];
#pragma unroll
  for (int i = 0; i < 4; ++i) {
    int rowb = m0 + wm * 64 + i * 16 + qlane * 4;
#pragma unroll
    for (int j = 0; j < 4; ++j) {
      int col = cb + j * 16 + r;
#pragma unroll
      for (int v = 0; v < 4; ++v) {
        float val = acc[i][j][v] + bvv[j];
        size_t off = (size_t)(rowb + v) * 1024 + col;
        if (out_mode == 0)      ((bf16*)Cout)[off] = (bf16)val;
        else if (out_mode == 1) ((f16*)Cout)[off] = (f16)val;
        else                    ((float*)Cout)[off] = val;
      }
    }
  }
}

// u and v projections fused via grid.z (0: u bf16, 1: v f16).
__global__ __launch_bounds__(512, 4)
void gemm_uv_k(const bf16* __restrict__ A, const bf16* __restrict__ WuT,
               const bf16* __restrict__ WvT, const float* __restrict__ bu,
               const float* __restrict__ bv, bf16* __restrict__ u_out,
               f16* __restrict__ v_out) {
  const int isv = blockIdx.z;
  gemm_body_occ(A, isv ? WvT : WuT, isv ? bv : bu,
                isv ? (void*)v_out : (void*)u_out, isv,
                blockIdx.x * 256, blockIdx.y * 128);
}

// final projection: C f32
__global__ __launch_bounds__(512, 4)
void gemm_o_k(const bf16* __restrict__ A, const bf16* __restrict__ Bt,
              const float* __restrict__ bias, float* __restrict__ C) {
  gemm_body_occ(A, Bt, bias, (void*)C, 2, blockIdx.x * 256, blockIdx.y * 128);
}

// ---------------------------------------------------------------------------
// Truncated causal depthwise conv (T=512) + gate, packed f16x2 along d.
// Block: 64 d (32 __half2 pairs) x 128 t; thread: 1 d-pair, 16 t.
// Chunk = 64 lags; acc in f16x2 per chunk, flushed to f32. All inner-loop
// math is v_pk_fma_f16 (2 MACs/inst); zero cvts in the hot loop.
// LDS: vs 192x32 u32 (24KB) + hs 64x32 u32 (8KB) = 32KB -> 5 blocks/CU.
// (Invariant at ~182 us across 3 structural rewrites; kept verbatim.
//  Round-9: back to the MERGED launch (16,32,4) -- round-8's per-batch
//  split cost +45 us by leaving 3/4 of the chip idle per dispatch.)
// ---------------------------------------------------------------------------
__global__ __launch_bounds__(256)
void conv_k(const f16* __restrict__ vg0, const f16* __restrict__ hp,
            bf16* __restrict__ up0) {
  constexpr int CC = 64, TT = 128, D = 1024;
  __shared__ __align__(16) unsigned vs2[(TT + CC) * 32];  // [row][pair] 24KB
  __shared__ __align__(16) unsigned hs2[CC * 32];         // [kk][pair]   8KB
  const int tid = threadIdx.x;
  const int pp = tid & 31, tg = tid >> 5;
  const int bx = blockIdx.x;                 // d0 = bx*64
  const int t0 = blockIdx.y * TT;
  const int base = tg * 16;
  const unsigned* vg32 = (const unsigned*)(vg0 + (size_t)blockIdx.z * 4096 * D);
  unsigned* up32 = (unsigned*)(up0 + (size_t)blockIdx.z * 4096 * D);
  const uintx4* vg4 = (const uintx4*)vg32;             // 128 u4 per t-row
  const uintx4* hp4 = (const uintx4*)hp + (size_t)bx * 512 * 8;  // 8 u4/row

  float ax[16], ay[16];
#pragma unroll
  for (int i = 0; i < 16; ++i) { ax[i] = 0.f; ay[i] = 0.f; }

  for (int c = 0; c < 8; ++c) {
    const int k0 = c * CC;
    __syncthreads();   // prev chunk's reads complete before restage
    {  // stage h chunk: 64 rows x 8 u4 = 512 u4
      uintx4* hd = (uintx4*)hs2;
      hd[tid] = hp4[k0 * 8 + tid];
      hd[tid + 256] = hp4[k0 * 8 + tid + 256];
    }
    {  // stage v window rows [t0-k0-64, t0+127]: 192 x 8 u4 = 1536 u4
      uintx4* vd = (uintx4*)vs2;
#pragma unroll
      for (int it = 0; it < 6; ++it) {
        int q = it * 256 + tid;
        int row = q >> 3, dp4 = q & 7;
        int tau = t0 - k0 - CC + row;
        uintx4 val = {0, 0, 0, 0};
        if (tau >= 0) val = vg4[(size_t)tau * 128 + bx * 8 + dp4];
        vd[q] = val;
      }
    }
    __syncthreads();

    __half2 p[16];
#pragma unroll
    for (int i = 0; i < 16; ++i)
      p[i] = u2h2(vs2[(base + i + CC) * 32 + pp]);     // v[t_i - k0]
    __half2 acc2[16];
    const __half2 z2 = __float2half2_rn(0.f);
#pragma unroll
    for (int i = 0; i < 16; ++i) acc2[i] = z2;

    for (int kb = 0; kb < 4; ++kb) {
#pragma unroll
      for (int k2 = 0; k2 < 16; ++k2) {
        const int kk = kb * 16 + k2;
        __half2 hk = u2h2(hs2[kk * 32 + pp]);
#pragma unroll
        for (int i = 0; i < 16; ++i)
          acc2[i] = __hfma2(hk, p[(i - k2) & 15], acc2[i]);
        p[(15 - k2) & 15] = u2h2(vs2[(base + CC - 1 - kk) * 32 + pp]);
      }
    }
#pragma unroll
    for (int i = 0; i < 16; ++i) {
      ax[i] += __low2float(acc2[i]);
      ay[i] += __high2float(acc2[i]);
    }
  }

  // gate: p = u * v_conv, in-place over u; one u32 = 2 bf16 per row
  const size_t rb = (size_t)(t0 + base) * 512 + bx * 32 + pp;
#pragma unroll
  for (int i = 0; i < 16; ++i) {
    unsigned uw = up32[rb + (size_t)i * 512];
    float ul = __uint_as_float((uw & 0xffffu) << 16);
    float uh = __uint_as_float(uw & 0xffff0000u);
    unsigned lo = bf16_bits(ul * ax[i]);
    unsigned hi = bf16_bits(uh * ay[i]);
    up32[rb + (size_t)i * 512] = lo | (hi << 16);
  }
}

// ---------------------------------------------------------------------------
// All inputs/outputs are FLOAT32. Internals bf16/f16.
// BIG path (ws_size >= 41 MB): full-M merged dispatches.
//   ws:   WuT 0..2MB | WvT 2..4 | WoT 4..6 | hp 6..7 | u 8..40MB (bf16)
//   d_out: xb (bf16) 0..32MB | v (f16) 32..64MB; gemm_o overwrites with f32.
// COMPACT path: per-batch loop.
// ---------------------------------------------------------------------------
extern "C" void kernel_launch(void* const* d_in, const int* in_sizes, int n_in,
                              void* d_out, int out_size, void* d_ws,
                              size_t ws_size, hipStream_t stream) {
  const float* x  = (const float*)d_in[0];
  const float* Wu = (const float*)d_in[1];
  const float* bu = (const float*)d_in[2];
  const float* Wv = (const float*)d_in[3];
  const float* bv = (const float*)d_in[4];
  const float* hf = (const float*)d_in[5];
  const float* Wo = (const float*)d_in[6];
  const float* bo = (const float*)d_in[7];
  char* ws = (char*)d_ws;
  bf16* WuT = (bf16*)(ws);
  bf16* WvT = (bf16*)(ws + 2097152);
  bf16* WoT = (bf16*)(ws + 4194304);
  f16*  hp  = (f16*)(ws + 6291456);

  dim3 tb(256);
  dim3 tg(512);
  transpose_k<<<dim3(16, 16, 3), tb, 0, stream>>>(Wu, Wv, Wo, WuT, WvT, WoT);
  hprep_k<<<dim3(2048), tb, 0, stream>>>(hf, hp);

  if (ws_size >= 42991616ull) {           // BIG: 41 MB needed
    bf16* xb = (bf16*)d_out;
    f16*  vf = (f16*)((char*)d_out + 33554432);
    bf16* u  = (bf16*)(ws + 8388608);
    cvtx_k<<<dim3(8192), tb, 0, stream>>>(x, (char*)d_out, 8388608);
    gemm_uv_k<<<dim3(64, 8, 2), tg, 0, stream>>>(xb, WuT, WvT, bu, bv, u, vf);
    conv_k<<<dim3(16, 32, 4), tb, 0, stream>>>(vf, hp, u);
    gemm_o_k<<<dim3(64, 8), tg, 0, stream>>>(u, WoT, bo, (float*)d_out);
  } else {                                // COMPACT: per-batch loop
    bf16* u_b = (bf16*)(ws + 8388608);
    cvtx_k<<<dim3(8192), tb, 0, stream>>>(x, (char*)d_out, 16777216);
    for (int b = 0; b < 4; ++b) {
      char* quarter = (char*)d_out + (size_t)b * 16777216;
      bf16* xb = (bf16*)quarter;
      f16*  vb = (f16*)(quarter + 8388608);
      float* outb = (float*)d_out + (size_t)b * 4194304;
      gemm_uv_k<<<dim3(16, 8, 2), tg, 0, stream>>>(xb, WuT, WvT, bu, bv,
                                                   u_b, vb);
      conv_k<<<dim3(16, 32, 1), tb, 0, stream>>>(vb, hp, u_b);
      gemm_o_k<<<dim3(16, 8), tg, 0, stream>>>(u_b, WoT, bo, outb);
    }
  }
}